// Round 8
// baseline (28.655 us; speedup 1.0000x reference)
//
#include <hip/hip_runtime.h>
#include <hip/hip_bf16.h>
#include <float.h>

// VQ bottleneck, SINGLE dispatch. encoded: (2048,256) f32, emb: (1,256,512) f32.
// out: latent (2048*256) f32 ++ loss (1) f32.
//
// Block b owns dim b: bitonic sort (shfl j<64, LDS j>=64) keeps the sorted
// (val, original-idx) table in LDS; 4 interleaved binary-search chains
// quantize all 2048 samples of column b. d2 = fl(fl(x-c)^2) is monotone in
// |x-c| per side => argmin is one of the two sorted neighbors; original
// indices reproduce np.argmin's first-index tie-break exactly.
//
// Loss without a second dispatch and without a zeroed counter:
// block b publishes its partial as (MAGIC<<32)|float_bits via device-scope
// release store (cross-XCD visible); block 0 acquire-polls all 256 slots for
// MAGIC, then reduces in fixed order. Stale slots from a previous replay hold
// the SAME deterministic value, so re-reading them is harmless; the 0xAA..
// poison never matches MAGIC. Only block 0 spins -> deadlock-free.

#define NSAMP 2048
#define NDIM  256
#define NCODE 512
#define MAGIC 0xC0FFEE42u

__global__ __launch_bounds__(512)
void vq_onepass(const float* __restrict__ enc,
                const float* __restrict__ emb,
                float* __restrict__ out,
                unsigned long long* __restrict__ slot)
{
    __shared__ float sv[NCODE];
    __shared__ int   si[NCODE];
    __shared__ float red[8];

    const int tid = threadIdx.x;
    const int b   = blockIdx.x;            // one block per dimension

    // ================= phase 1: bitonic sort of codebook dim b =================
    {
        float v  = emb[b * NCODE + tid];
        int  idx = tid;
        for (int k = 2; k <= NCODE; k <<= 1) {
            for (int j = k >> 1; j > 0; j >>= 1) {
                float v2; int i2;
                if (j < 64) {
                    v2 = __shfl_xor(v, j, 64);
                    i2 = __shfl_xor(idx, j, 64);
                } else {
                    sv[tid] = v; si[tid] = idx;
                    __syncthreads();
                    v2 = sv[tid ^ j]; i2 = si[tid ^ j];
                    __syncthreads();
                }
                // total order (val, idx): exact handling of duplicate values
                bool less  = (v < v2) || (v == v2 && idx < i2);
                bool lower = (tid & j) == 0;
                bool up    = (tid & k) == 0;   // k==512: final ascending merge
                if ((lower == up) != less) { v = v2; idx = i2; }
            }
        }
        sv[tid] = v;        // sorted table stays resident in LDS
        si[tid] = idx;
    }
    __syncthreads();

    // ========== phase 2: 4 interleaved binary-search chains ==========
    float x[4];
#pragma unroll
    for (int r = 0; r < 4; ++r)
        x[r] = enc[(tid + 512 * r) * NDIM + b];

    int p[4] = {0, 0, 0, 0};
#pragma unroll
    for (int s = NCODE / 2; s > 0; s >>= 1) {
#pragma unroll
        for (int r = 0; r < 4; ++r)
            if (sv[p[r] + s - 1] < x[r]) p[r] += s;   // p = #(val < x), capped 511
    }

    float acc = 0.0f;
#pragma unroll
    for (int r = 0; r < 4; ++r) {
        int pp = p[r];
        if (sv[pp] < x[r]) ++pp;                      // count==512 fixup
        float d2l = FLT_MAX, d2r = FLT_MAX, vl = 0.0f, vr = 0.0f;
        int il = 0x7fffffff, ir = 0x7fffffff;
        if (pp > 0)     { vl = sv[pp - 1]; il = si[pp - 1]; float t = x[r] - vl; d2l = t * t; }
        if (pp < NCODE) { vr = sv[pp];     ir = si[pp];     float t = x[r] - vr; d2r = t * t; }
        out[(tid + 512 * r) * NDIM + b] =
            (d2l < d2r) ? vl : (d2r < d2l) ? vr : ((il < ir) ? vl : vr);
        acc += fminf(d2l, d2r);
    }

    // ================= phase 3: publish per-block partial =================
#pragma unroll
    for (int off = 32; off > 0; off >>= 1)
        acc += __shfl_down(acc, off, 64);
    if ((tid & 63) == 0) red[tid >> 6] = acc;
    __syncthreads();
    if (tid == 0) {
        float s = 0.0f;
#pragma unroll
        for (int w = 0; w < 8; ++w) s += red[w];
        unsigned long long u = ((unsigned long long)MAGIC << 32) |
                               (unsigned long long)__float_as_uint(s);
        __hip_atomic_store(&slot[b], u, __ATOMIC_RELEASE, __HIP_MEMORY_SCOPE_AGENT);
    }

    // ================= phase 4: block 0 polls + reduces =================
    if (b == 0) {
        float a2 = 0.0f;
        if (tid < NDIM) {
            unsigned long long u;
            do {
                u = __hip_atomic_load(&slot[tid], __ATOMIC_ACQUIRE,
                                      __HIP_MEMORY_SCOPE_AGENT);
            } while ((unsigned)(u >> 32) != MAGIC);
            a2 = __uint_as_float((unsigned)(u & 0xFFFFFFFFull));
        }
#pragma unroll
        for (int off = 32; off > 0; off >>= 1)
            a2 += __shfl_down(a2, off, 64);
        if ((tid & 63) == 0) red[tid >> 6] = a2;     // fixed-order partials
        __syncthreads();
        if (tid == 0)
            out[NSAMP * NDIM] = 2.0f * (red[0] + red[1] + red[2] + red[3]);
    }
}

extern "C" void kernel_launch(void* const* d_in, const int* in_sizes, int n_in,
                              void* d_out, int out_size, void* d_ws, size_t ws_size,
                              hipStream_t stream)
{
    const float* enc = (const float*)d_in[0];   // (2048, 256)
    const float* emb = (const float*)d_in[1];   // (1, 256, 512)
    float* out = (float*)d_out;                 // latent ++ loss
    unsigned long long* slot = (unsigned long long*)d_ws;  // 256 tagged partials

    vq_onepass<<<NDIM, 512, 0, stream>>>(enc, emb, out, slot);
}

// Round 9
// 21.785 us; speedup vs baseline: 1.3153x; 1.3153x over previous
//
#include <hip/hip_runtime.h>
#include <hip/hip_bf16.h>
#include <float.h>

// VQ bottleneck — FINAL: empirically fastest structure (21.7us) out of 8
// structural variants. 3 plain dispatches; every "clever" alternative
// (cooperative grid.sync, graph memset node, last-block atomics, spin-poll)
// measured slower on this runtime. Kernel work is ~5us; the rest of dur_us
// is fixed graph-replay overhead.
//
// encoded: (2048, 256) f32, emb: (1, 256, 512) f32.
// out: latent (2048*256) f32 ++ loss (1) f32.
//
// Algorithm: per-dim scalar quantization. d2 = fl(fl(x-c)^2) is monotone in
// |x-c| on each side of x, so the argmin over 512 codes is one of the two
// sorted-order neighbors of x. Sort each dim's codebook once (carrying
// original indices), then binary-search each element. Carrying indices
// reproduces np.argmin's first-index tie-break exactly (duplicate values /
// exact-midpoint cases). Verified absmax 0.0 across all rounds.

#define NSAMP 2048
#define NDIM  256
#define NCODE 512
#define DT    16
#define ST    128
#define CBS   516   // 512+4 pad: 16B-aligned rows, conflict-free probes

// ---- ws layout ----
#define WS_VAL_OFF  0
#define WS_IDX_OFF  (NDIM * NCODE * 4)                  // 512 KB
#define WS_LOSS_OFF (WS_IDX_OFF + NDIM * NCODE * 2)     // 768 KB

// ================= kernel 1: per-dim bitonic sort =================
// 256 blocks x 512 threads; stages j<64 via __shfl_xor, j>=64 via LDS.
__global__ __launch_bounds__(512)
void vq_sort(const float* __restrict__ emb,
             float* __restrict__ wsVal,
             unsigned short* __restrict__ wsIdx)
{
    __shared__ float sv[NCODE];
    __shared__ int   si[NCODE];
    const int tid = threadIdx.x;
    const int d   = blockIdx.x;
    float v  = emb[d * NCODE + tid];
    int  idx = tid;
    for (int k = 2; k <= NCODE; k <<= 1) {
        for (int j = k >> 1; j > 0; j >>= 1) {
            float v2; int i2;
            if (j < 64) {
                v2 = __shfl_xor(v, j, 64);
                i2 = __shfl_xor(idx, j, 64);
            } else {
                sv[tid] = v; si[tid] = idx;
                __syncthreads();
                v2 = sv[tid ^ j]; i2 = si[tid ^ j];
                __syncthreads();
            }
            // total order (val, idx): exact handling of duplicate values
            bool less  = (v < v2) || (v == v2 && idx < i2);
            bool lower = (tid & j) == 0;
            bool up    = (tid & k) == 0;   // k==512: final ascending merge
            if ((lower == up) != less) { v = v2; idx = i2; }
        }
    }
    wsVal[d * NCODE + tid] = v;
    wsIdx[d * NCODE + tid] = (unsigned short)idx;
}

// ================= kernel 2: coalesced binary-search quantize =================
// Block = 16 dims x 128 samples (256 threads, 8 interleaved chains/thread).
__global__ __launch_bounds__(256)
void vq_search(const float* __restrict__ enc,
               const float* __restrict__ wsVal,
               const unsigned short* __restrict__ wsIdx,
               float* __restrict__ out,
               float* __restrict__ wsLoss)
{
    __shared__ float          cbv[DT][CBS];
    __shared__ unsigned short cbi[DT][CBS];
    __shared__ float red[4];

    const int tid   = threadIdx.x;
    const int bx    = blockIdx.x;
    const int dtile = bx & (NDIM / DT - 1);
    const int stile = bx >> 4;
    const int d0    = dtile * DT;
    const int n0    = stile * ST;

    // ---- stage sorted tables into LDS (coalesced) ----
    {
        const float4* src = reinterpret_cast<const float4*>(wsVal + d0 * NCODE);
        for (int i4 = tid; i4 < DT * NCODE / 4; i4 += 256) {
            float4 q = src[i4];
            int i = i4 * 4, dl2 = i >> 9, pos = i & (NCODE - 1);
            *reinterpret_cast<float4*>(&cbv[dl2][pos]) = q;
        }
        const uint2* srci = reinterpret_cast<const uint2*>(wsIdx + d0 * NCODE);
        for (int i4 = tid; i4 < DT * NCODE / 4; i4 += 256) {
            uint2 q = srci[i4];
            int i = i4 * 4, dl2 = i >> 9, pos = i & (NCODE - 1);
            *reinterpret_cast<uint2*>(&cbi[dl2][pos]) = q;
        }
    }
    __syncthreads();

    const int dl = tid & (DT - 1);
    const float*          vrow = cbv[dl];
    const unsigned short* irow = cbi[dl];

    float x[8]; int gidx[8];
#pragma unroll
    for (int r = 0; r < 8; ++r) {
        int nl = (tid >> 4) + 16 * r;
        gidx[r] = (n0 + nl) * NDIM + d0 + dl;
        x[r] = enc[gidx[r]];
    }

    // ---- 8 interleaved branchless binary searches: p = #(val < x) ----
    int p[8];
#pragma unroll
    for (int r = 0; r < 8; ++r) p[r] = 0;
#pragma unroll
    for (int s = NCODE / 2; s > 0; s >>= 1) {
#pragma unroll
        for (int r = 0; r < 8; ++r)
            if (vrow[p[r] + s - 1] < x[r]) p[r] += s;
    }

    float acc = 0.0f;
#pragma unroll
    for (int r = 0; r < 8; ++r) {
        int pp = p[r];
        if (vrow[pp] < x[r]) ++pp;          // count==512 fixup
        float d2l = FLT_MAX, d2r = FLT_MAX, vl = 0.0f, vr = 0.0f;
        int il = 0x7fffffff, ir = 0x7fffffff;
        if (pp > 0)     { vl = vrow[pp - 1]; il = irow[pp - 1]; float t = x[r] - vl; d2l = t * t; }
        if (pp < NCODE) { vr = vrow[pp];     ir = irow[pp];     float t = x[r] - vr; d2r = t * t; }
        out[gidx[r]] = (d2l < d2r) ? vl : (d2r < d2l) ? vr : ((il < ir) ? vl : vr);
        acc += fminf(d2l, d2r);
    }

    // ---- block partial of sum(min d2) ----
#pragma unroll
    for (int off = 32; off > 0; off >>= 1)
        acc += __shfl_down(acc, off, 64);
    if ((tid & 63) == 0) red[tid >> 6] = acc;
    __syncthreads();
    if (tid == 0)
        wsLoss[bx] = red[0] + red[1] + red[2] + red[3];
}

// ================= kernel 3: final deterministic loss reduce =================
__global__ __launch_bounds__(256)
void vq_final(const float* __restrict__ wsLoss, float* __restrict__ out)
{
    __shared__ float red[4];
    const int tid = threadIdx.x;
    float acc = wsLoss[tid];              // 256 partials, fixed order
#pragma unroll
    for (int off = 32; off > 0; off >>= 1)
        acc += __shfl_down(acc, off, 64);
    if ((tid & 63) == 0) red[tid >> 6] = acc;
    __syncthreads();
    if (tid == 0)
        out[NSAMP * NDIM] = 2.0f * (red[0] + red[1] + red[2] + red[3]);
}

extern "C" void kernel_launch(void* const* d_in, const int* in_sizes, int n_in,
                              void* d_out, int out_size, void* d_ws, size_t ws_size,
                              hipStream_t stream)
{
    const float* enc = (const float*)d_in[0];   // (2048, 256)
    const float* emb = (const float*)d_in[1];   // (1, 256, 512)
    float* out = (float*)d_out;                 // latent ++ loss

    char* ws = (char*)d_ws;
    float*          wsVal  = (float*)(ws + WS_VAL_OFF);
    unsigned short* wsIdx  = (unsigned short*)(ws + WS_IDX_OFF);
    float*          wsLoss = (float*)(ws + WS_LOSS_OFF);

    vq_sort  <<<NDIM, 512, 0, stream>>>(emb, wsVal, wsIdx);
    vq_search<<<(NSAMP / ST) * (NDIM / DT), 256, 0, stream>>>(enc, wsVal, wsIdx, out, wsLoss);
    vq_final <<<1, NDIM, 0, stream>>>(wsLoss, out);
}